// Round 11
// baseline (139.214 us; speedup 1.0000x reference)
//
#include <hip/hip_runtime.h>
#include <hip/hip_fp16.h>

// retina_polar2: log-polar glimpse sampling + 10x10 avg-pool
// x: [64,3,512,512] f32 | l_t_prev: [64,2] f32 | grid_2d: [320,640,2] f32
// out: [64,3,32,64] f32
//
// Round-11: gather-phase load balance. r10 ran gather at ~49% thread
// utilization (outer bands had 40-160 items on 256 threads). Re-band with
// radial split R (item = theta x win x radial-phase, S=10/R samples each)
// so every block runs 78-94% full:
//   A<w0 ,G8,T40,R2>  B<w8 ,G7,T40,R5>  C<w15,G6,T40,R1>  D<w21,G4,T40,R5>
//   E<w25,G2,T40,R5>  F<w27,G2,T20,R5>  G<w29,G2,T20,R5>  H<w31,G1,T20,R10>
// All band extents verified <= ~58px vs 64x68 f16 tile (34.8 KB, 4 blk/CU).
// Analytic bbox, interior fast path, f16 interleaved {c0,c1,c2,pad} tile,
// one ds_read_b64 per bilinear tap, division-free float4 staging: as r10.

#define HI_ 512
#define WI_ 512
#define B_  64
#define PLANE_ (HI_ * WI_)
#define PITCH 68
#define TILEPIX (64 * PITCH)   // 4352 pixels * 8 B = 34816 B

__device__ __forceinline__ void dec3(const __half* __restrict__ s, int pix,
                                     float2& f01, float& c) {
    const uint2 q = *reinterpret_cast<const uint2*>(s + 4 * pix);
    f01 = __half22float2(*reinterpret_cast<const __half2*>(&q.x));
    const unsigned short hu = (unsigned short)(q.y & 0xffffu);
    c = __half2float(*reinterpret_cast<const __half*>(&hu));
}

template<int SB>
__device__ __forceinline__ void tapBatch(
    const __half* __restrict__ simg,
    const int* __restrict__ pp,
    const float* __restrict__ wxv,
    const float* __restrict__ wyv,
    float2& s01, float& s2)
{
    float2 f00[SB], f01v[SB], f10[SB], f11[SB];
    float  c00[SB], c01[SB], c10[SB], c11[SB];
    #pragma unroll
    for (int j = 0; j < SB; ++j) {
        const int p = pp[j];
        dec3(simg, p,             f00[j],  c00[j]);
        dec3(simg, p + 1,         f01v[j], c01[j]);
        dec3(simg, p + PITCH,     f10[j],  c10[j]);
        dec3(simg, p + PITCH + 1, f11[j],  c11[j]);
    }
    #pragma unroll
    for (int j = 0; j < SB; ++j) {
        const float w11 = wxv[j] * wyv[j];
        const float w10 = wyv[j] - w11;
        const float w01 = wxv[j] - w11;
        const float w00 = 1.0f - wxv[j] - wyv[j] + w11;
        s01.x += f00[j].x*w00 + f01v[j].x*w01 + f10[j].x*w10 + f11[j].x*w11;
        s01.y += f00[j].y*w00 + f01v[j].y*w01 + f10[j].y*w10 + f11[j].y*w11;
        s2    += c00[j]  *w00 + c01[j]  *w01 + c10[j]  *w10 + c11[j]  *w11;
    }
}

template<int W0, int G, int T, int R, bool INT>
__device__ __forceinline__ void gatherLoop(
    const int tid, const int th0,
    const float* __restrict__ grid,
    const __half* __restrict__ simg,
    float* __restrict__ sacc,
    const float sx, const float sy,
    const int xs4, const int y_lo, const int wmax, const int hmax)
{
    constexpr int TC    = T / 10;
    constexpr int S     = 10 / R;        // samples per item
    constexpr int ITEMS = T * G * R;
    for (int it = tid; it < ITEMS; it += 256) {
        const int tl   = it % T;
        const int u    = it / T;
        const int rph  = u % R;
        const int win  = u / R;
        const int row0 = (W0 + win) * 10 + rph * S;

        int   pp [S];
        float wxv[S], wyv[S];
        #pragma unroll
        for (int j = 0; j < S; ++j) {
            const float2 g = *reinterpret_cast<const float2*>(
                grid + ((size_t)(row0 + j) * 640 + th0 + tl) * 2);
            float ix = fmaf(g.x, 256.0f, sx);
            float iy = fmaf(g.y, 256.0f, sy);
            if (!INT) {
                ix = fminf(fmaxf(ix, 0.0f), 511.0f);
                iy = fminf(fmaxf(iy, 0.0f), 511.0f);
            }
            const float x0f = floorf(ix);
            const float y0f = floorf(iy);
            int col = (int)x0f - xs4;
            int row = (int)y0f - y_lo;
            if (!INT) {
                col = min(max(col, 0), wmax);
                row = min(max(row, 0), hmax);
            }
            pp [j] = row * PITCH + col;
            wxv[j] = ix - x0f;
            wyv[j] = iy - y0f;
        }

        float2 s01 = make_float2(0.0f, 0.0f);
        float  s2  = 0.0f;
        if (S == 10) {
            tapBatch<5>(simg, pp,     wxv,     wyv,     s01, s2);
            tapBatch<5>(simg, pp + 5, wxv + 5, wyv + 5, s01, s2);
        } else {
            tapBatch<S>(simg, pp, wxv, wyv, s01, s2);
        }

        const int tc = tl / 10;
        atomicAdd(&sacc[(0 * G + win) * TC + tc], s01.x);
        atomicAdd(&sacc[(1 * G + win) * TC + tc], s01.y);
        atomicAdd(&sacc[(2 * G + win) * TC + tc], s2);
    }
}

template<int W0, int G, int T, int R>
__device__ __forceinline__ void band(
    const int b, const int slot,
    const float* __restrict__ x,
    const float* __restrict__ grid,
    float* __restrict__ out,
    const float sx, const float sy,
    __half* __restrict__ simg,
    float*  __restrict__ sacc)
{
    constexpr int TC   = T / 10;
    constexpr int ACCN = 3 * G * TC;
    const int tid = threadIdx.x;
    const int th0 = slot * T;

    if (tid < ACCN) sacc[tid] = 0.0f;

    // ---- analytic bbox (exact range of 256*r*sin/cos over the band) ----
    const float CT  = 6.283185307179586f / 640.0f;
    const float tha = th0 * CT, thb = (th0 + T - 1) * CT;
    const float LN001 = -4.605170185988091f;          // ln 0.01
    const float LSTEP = 4.0943445622221004f / 319.0f; // ln 60 / 319
    const float r_lo  = expf(fmaf((float)(10 * W0),           LSTEP, LN001));
    const float r_hi  = expf(fmaf((float)(10 * (W0 + G) - 1), LSTEP, LN001));
    const float plo = 256.0f * r_lo, phi = 256.0f * r_hi;

    const float sa = sinf(tha), sb = sinf(thb);
    const float ca = cosf(tha), cb = cosf(thb);
    const float smax = (tha < 1.5707965f && thb > 1.5707962f) ?  1.0f : fmaxf(sa, sb);
    const float smin = (tha < 4.7123892f && thb > 4.7123888f) ? -1.0f : fminf(sa, sb);
    const float cmax = fmaxf(ca, cb);
    const float cmin = (tha < 3.1415928f && thb > 3.1415925f) ? -1.0f : fminf(ca, cb);

    const float ixmin = fminf(fminf(plo*smin, phi*smin), fminf(plo*smax, phi*smax)) + sx;
    const float ixmax = fmaxf(fmaxf(plo*smin, phi*smin), fmaxf(plo*smax, phi*smax)) + sx;
    const float iymin = fminf(fminf(plo*cmin, phi*cmin), fminf(plo*cmax, phi*cmax)) + sy;
    const float iymax = fmaxf(fmaxf(plo*cmin, phi*cmin), fmaxf(plo*cmax, phi*cmax)) + sy;

    const int x_lo = max(0, (int)floorf(ixmin - 0.5f));
    const int x_hi = min(511, (int)ceilf(ixmax + 0.5f));
    const int y_lo = max(0, (int)floorf(iymin - 0.5f));
    const int y_hi = min(511, (int)ceilf(iymax + 0.5f));

    const int xs4 = x_lo & ~3;
    const int W4  = min(PITCH / 4, ((x_hi + 1 - xs4) >> 2) + 1);
    const int H   = min(64, y_hi - y_lo + 2);
    const int wmax = (W4 << 2) - 2;
    const int hmax = H - 2;

    const bool interior = (ixmin > 1.0f) && (ixmax < 510.0f) &&
                          (iymin > 1.0f) && (iymax < 510.0f);

    const float* __restrict__ xb = x + (size_t)b * 3 * PLANE_;

    // ---- stage: division-free, float4-coalesced, f16 interleaved ----
    const int lane16 = tid & 15;
    const int rowB   = tid >> 4;
    for (int row = rowB; row < H; row += 16) {
        const int ys = min(y_lo + row, 511);
        const float* __restrict__ r0 = xb + ys * 512;
        for (int c4 = lane16; c4 < W4; c4 += 16) {
            const int xb0 = xs4 + (c4 << 2);
            float v0[4], v1[4], v2[4];
            if (xb0 <= 508) {
                *reinterpret_cast<float4*>(v0) = *reinterpret_cast<const float4*>(r0 + xb0);
                *reinterpret_cast<float4*>(v1) = *reinterpret_cast<const float4*>(r0 + PLANE_ + xb0);
                *reinterpret_cast<float4*>(v2) = *reinterpret_cast<const float4*>(r0 + 2 * PLANE_ + xb0);
            } else {
                #pragma unroll
                for (int p = 0; p < 4; ++p) {
                    const int xs = min(xb0 + p, 511);
                    v0[p] = r0[xs];
                    v1[p] = r0[PLANE_ + xs];
                    v2[p] = r0[2 * PLANE_ + xs];
                }
            }
            const int pix0 = row * PITCH + (c4 << 2);
            #pragma unroll
            for (int p = 0; p < 4; ++p) {
                __half* d = simg + 4 * (pix0 + p);
                *reinterpret_cast<__half2*>(d) = __floats2half2_rn(v0[p], v1[p]);
                d[2] = __float2half_rn(v2[p]);
            }
        }
    }
    __syncthreads();

    if (interior)
        gatherLoop<W0, G, T, R, true >(tid, th0, grid, simg, sacc, sx, sy, xs4, y_lo, wmax, hmax);
    else
        gatherLoop<W0, G, T, R, false>(tid, th0, grid, simg, sacc, sx, sy, xs4, y_lo, wmax, hmax);
    __syncthreads();

    if (tid < ACCN) {
        const int c   = tid / (G * TC);
        const int rem = tid - c * (G * TC);
        const int win = rem / TC;
        const int tc  = rem - win * TC;
        out[(((size_t)b * 3 + c) * 32 + W0 + win) * 64 + (th0 / 10) + tc] =
            sacc[tid] * 0.01f;
    }
}

__global__ __launch_bounds__(256, 4) void retina_polar_staged(
    const float* __restrict__ x,
    const float* __restrict__ lt,
    const float* __restrict__ grid,
    float* __restrict__ out)
{
    __shared__ __half simg[TILEPIX * 4];   // 34816 B
    __shared__ float  sacc[96];

    const int bid = blockIdx.x;
    const int b   = bid / 176;
    const int r   = bid - b * 176;
    const float sx = fmaf(lt[b * 2 + 0], 256.0f, 255.5f);
    const float sy = fmaf(lt[b * 2 + 1], 256.0f, 255.5f);

    if      (r <  16) band< 0, 8, 40,  2>(b, r,       x, grid, out, sx, sy, simg, sacc);
    else if (r <  32) band< 8, 7, 40,  5>(b, r - 16,  x, grid, out, sx, sy, simg, sacc);
    else if (r <  48) band<15, 6, 40,  1>(b, r - 32,  x, grid, out, sx, sy, simg, sacc);
    else if (r <  64) band<21, 4, 40,  5>(b, r - 48,  x, grid, out, sx, sy, simg, sacc);
    else if (r <  80) band<25, 2, 40,  5>(b, r - 64,  x, grid, out, sx, sy, simg, sacc);
    else if (r < 112) band<27, 2, 20,  5>(b, r - 80,  x, grid, out, sx, sy, simg, sacc);
    else if (r < 144) band<29, 2, 20,  5>(b, r - 112, x, grid, out, sx, sy, simg, sacc);
    else              band<31, 1, 20, 10>(b, r - 144, x, grid, out, sx, sy, simg, sacc);
}

extern "C" void kernel_launch(void* const* d_in, const int* in_sizes, int n_in,
                              void* d_out, int out_size, void* d_ws, size_t ws_size,
                              hipStream_t stream)
{
    const float* x    = (const float*)d_in[0];
    const float* lt   = (const float*)d_in[1];
    const float* grid = (const float*)d_in[2];
    float* out        = (float*)d_out;

    retina_polar_staged<<<dim3(B_ * 176), dim3(256), 0, stream>>>(x, lt, grid, out);
}

// Round 12
// 68.330 us; speedup vs baseline: 2.0374x; 2.0374x over previous
//
#include <hip/hip_runtime.h>
#include <hip/hip_fp16.h>

// retina_polar2: log-polar glimpse sampling + 10x10 avg-pool
// x: [64,3,512,512] f32 | l_t_prev: [64,2] f32 | grid_2d: [320,640,2] f32
// out: [64,3,32,64] f32
//
// Round-12: r10 structure (144 balanced blocks/image, f16 interleaved
// {c0,c1,c2,pad} tile, one ds_read_b64 per tap, analytic bbox, interior
// fast path, division-free float4 staging) + atomic-free accumulation:
// item (theta,win) <-> slot (win,tc,ph=tl%10) is a BIJECTION, so each
// item writes its 3-channel partial with ONE plain ds_write_b128 (no
// atomics, no sacc zero-init); output pass sums the 10 radial-phase
// partials. r11's R-split banding reverted (post-mortem: lane-fill was
// never the constraint; it multiplied per-item overhead + staging).

#define HI_ 512
#define WI_ 512
#define B_  64
#define PLANE_ (HI_ * WI_)
#define PITCH 68
#define TILEPIX (64 * PITCH)   // 4352 pixels * 8 B = 34816 B

__device__ __forceinline__ void dec3(const __half* __restrict__ s, int pix,
                                     float2& f01, float& c) {
    const uint2 q = *reinterpret_cast<const uint2*>(s + 4 * pix);
    f01 = __half22float2(*reinterpret_cast<const __half2*>(&q.x));
    const unsigned short hu = (unsigned short)(q.y & 0xffffu);
    c = __half2float(*reinterpret_cast<const __half*>(&hu));
}

template<int W0, int G, int T, bool INT>
__device__ __forceinline__ void gatherLoop(
    const int tid, const int th0,
    const float* __restrict__ grid,
    const __half* __restrict__ simg,
    float* __restrict__ sacc,
    const float sx, const float sy,
    const int xs4, const int y_lo, const int wmax, const int hmax)
{
    constexpr int ITEMS = T * G;
    for (int it = tid; it < ITEMS; it += 256) {
        const int tl   = it % T;
        const int win  = it / T;
        const int grow = (W0 + win) * 10;

        int   pp [10];
        float wxv[10], wyv[10];
        #pragma unroll
        for (int j = 0; j < 10; ++j) {
            const float2 g = *reinterpret_cast<const float2*>(
                grid + ((size_t)(grow + j) * 640 + th0 + tl) * 2);
            float ix = fmaf(g.x, 256.0f, sx);
            float iy = fmaf(g.y, 256.0f, sy);
            if (!INT) {
                ix = fminf(fmaxf(ix, 0.0f), 511.0f);
                iy = fminf(fmaxf(iy, 0.0f), 511.0f);
            }
            const float x0f = floorf(ix);
            const float y0f = floorf(iy);
            int col = (int)x0f - xs4;
            int row = (int)y0f - y_lo;
            if (!INT) {
                col = min(max(col, 0), wmax);
                row = min(max(row, 0), hmax);
            }
            pp [j] = row * PITCH + col;
            wxv[j] = ix - x0f;
            wyv[j] = iy - y0f;
        }

        float2 s01 = make_float2(0.0f, 0.0f);
        float  s2  = 0.0f;
        #pragma unroll
        for (int hh = 0; hh < 2; ++hh) {
            float2 f00[5], f01v[5], f10[5], f11[5];
            float  c00[5], c01[5], c10[5], c11[5];
            #pragma unroll
            for (int j = 0; j < 5; ++j) {
                const int p = pp[hh * 5 + j];
                dec3(simg, p,             f00[j],  c00[j]);
                dec3(simg, p + 1,         f01v[j], c01[j]);
                dec3(simg, p + PITCH,     f10[j],  c10[j]);
                dec3(simg, p + PITCH + 1, f11[j],  c11[j]);
            }
            #pragma unroll
            for (int j = 0; j < 5; ++j) {
                const int rr = hh * 5 + j;
                const float w11 = wxv[rr] * wyv[rr];
                const float w10 = wyv[rr] - w11;
                const float w01 = wxv[rr] - w11;
                const float w00 = 1.0f - wxv[rr] - wyv[rr] + w11;
                s01.x += f00[j].x*w00 + f01v[j].x*w01 + f10[j].x*w10 + f11[j].x*w11;
                s01.y += f00[j].y*w00 + f01v[j].y*w01 + f10[j].y*w10 + f11[j].y*w11;
                s2    += c00[j]  *w00 + c01[j]  *w01 + c10[j]  *w10 + c11[j]  *w11;
            }
        }

        // bijective slot: (win, tc, ph) <-> it ; one b128 store, no atomic
        *reinterpret_cast<float4*>(&sacc[it * 4]) =
            make_float4(s01.x, s01.y, s2, 0.0f);
    }
}

template<int W0, int G, int T>
__device__ __forceinline__ void band(
    const int b, const int slot,
    const float* __restrict__ x,
    const float* __restrict__ grid,
    float* __restrict__ out,
    const float sx, const float sy,
    __half* __restrict__ simg,
    float*  __restrict__ sacc)
{
    constexpr int TC   = T / 10;
    constexpr int ACCN = 3 * G * TC;
    const int tid = threadIdx.x;
    const int th0 = slot * T;

    // ---- analytic bbox (exact range of 256*r*sin/cos over the band) ----
    const float CT  = 6.283185307179586f / 640.0f;
    const float tha = th0 * CT, thb = (th0 + T - 1) * CT;
    const float LN001 = -4.605170185988091f;          // ln 0.01
    const float LSTEP = 4.0943445622221004f / 319.0f; // ln 60 / 319
    const float r_lo  = expf(fmaf((float)(10 * W0),           LSTEP, LN001));
    const float r_hi  = expf(fmaf((float)(10 * (W0 + G) - 1), LSTEP, LN001));
    const float plo = 256.0f * r_lo, phi = 256.0f * r_hi;

    const float sa = sinf(tha), sb = sinf(thb);
    const float ca = cosf(tha), cb = cosf(thb);
    const float smax = (tha < 1.5707965f && thb > 1.5707962f) ?  1.0f : fmaxf(sa, sb);
    const float smin = (tha < 4.7123892f && thb > 4.7123888f) ? -1.0f : fminf(sa, sb);
    const float cmax = fmaxf(ca, cb);
    const float cmin = (tha < 3.1415928f && thb > 3.1415925f) ? -1.0f : fminf(ca, cb);

    const float ixmin = fminf(fminf(plo*smin, phi*smin), fminf(plo*smax, phi*smax)) + sx;
    const float ixmax = fmaxf(fmaxf(plo*smin, phi*smin), fmaxf(plo*smax, phi*smax)) + sx;
    const float iymin = fminf(fminf(plo*cmin, phi*cmin), fminf(plo*cmax, phi*cmax)) + sy;
    const float iymax = fmaxf(fmaxf(plo*cmin, phi*cmin), fmaxf(plo*cmax, phi*cmax)) + sy;

    const int x_lo = max(0, (int)floorf(ixmin - 0.5f));
    const int x_hi = min(511, (int)ceilf(ixmax + 0.5f));
    const int y_lo = max(0, (int)floorf(iymin - 0.5f));
    const int y_hi = min(511, (int)ceilf(iymax + 0.5f));

    const int xs4 = x_lo & ~3;
    const int W4  = min(PITCH / 4, ((x_hi + 1 - xs4) >> 2) + 1);
    const int H   = min(64, y_hi - y_lo + 2);
    const int wmax = (W4 << 2) - 2;
    const int hmax = H - 2;

    const bool interior = (ixmin > 1.0f) && (ixmax < 510.0f) &&
                          (iymin > 1.0f) && (iymax < 510.0f);

    const float* __restrict__ xb = x + (size_t)b * 3 * PLANE_;

    // ---- stage: division-free, float4-coalesced, f16 interleaved ----
    const int lane16 = tid & 15;
    const int rowB   = tid >> 4;
    for (int row = rowB; row < H; row += 16) {
        const int ys = min(y_lo + row, 511);
        const float* __restrict__ r0 = xb + ys * 512;
        for (int c4 = lane16; c4 < W4; c4 += 16) {
            const int xb0 = xs4 + (c4 << 2);
            float v0[4], v1[4], v2[4];
            if (xb0 <= 508) {
                *reinterpret_cast<float4*>(v0) = *reinterpret_cast<const float4*>(r0 + xb0);
                *reinterpret_cast<float4*>(v1) = *reinterpret_cast<const float4*>(r0 + PLANE_ + xb0);
                *reinterpret_cast<float4*>(v2) = *reinterpret_cast<const float4*>(r0 + 2 * PLANE_ + xb0);
            } else {
                #pragma unroll
                for (int p = 0; p < 4; ++p) {
                    const int xs = min(xb0 + p, 511);
                    v0[p] = r0[xs];
                    v1[p] = r0[PLANE_ + xs];
                    v2[p] = r0[2 * PLANE_ + xs];
                }
            }
            const int pix0 = row * PITCH + (c4 << 2);
            #pragma unroll
            for (int p = 0; p < 4; ++p) {
                __half* d = simg + 4 * (pix0 + p);
                *reinterpret_cast<__half2*>(d) = __floats2half2_rn(v0[p], v1[p]);
                d[2] = __float2half_rn(v2[p]);
            }
        }
    }
    __syncthreads();

    if (interior)
        gatherLoop<W0, G, T, true >(tid, th0, grid, simg, sacc, sx, sy, xs4, y_lo, wmax, hmax);
    else
        gatherLoop<W0, G, T, false>(tid, th0, grid, simg, sacc, sx, sy, xs4, y_lo, wmax, hmax);
    __syncthreads();

    // ---- output: sum the 10 radial-phase partials per (c,win,tc) ----
    if (tid < ACCN) {
        const int c   = tid / (G * TC);
        const int rem = tid - c * (G * TC);
        const int win = rem / TC;
        const int tc  = rem - win * TC;
        const int base = (win * T + tc * 10) * 4 + c;   // slot==it layout
        float s = 0.0f;
        #pragma unroll
        for (int ph = 0; ph < 10; ++ph)
            s += sacc[base + ph * 4];
        out[(((size_t)b * 3 + c) * 32 + W0 + win) * 64 + (th0 / 10) + tc] =
            s * 0.01f;
    }
}

__global__ __launch_bounds__(256, 4) void retina_polar_staged(
    const float* __restrict__ x,
    const float* __restrict__ lt,
    const float* __restrict__ grid,
    float* __restrict__ out)
{
    __shared__ __half simg[TILEPIX * 4];   // 34816 B
    __shared__ float  sacc[1280];          // 5120 B (max T*G=320 slots x4)

    const int bid = blockIdx.x;
    const int b   = bid / 144;
    const int r   = bid - b * 144;
    const float sx = fmaf(lt[b * 2 + 0], 256.0f, 255.5f);
    const float sy = fmaf(lt[b * 2 + 1], 256.0f, 255.5f);

    if      (r <  16) band< 0, 8, 40>(b, r,       x, grid, out, sx, sy, simg, sacc);
    else if (r <  32) band< 8, 7, 40>(b, r - 16,  x, grid, out, sx, sy, simg, sacc);
    else if (r <  48) band<15, 5, 40>(b, r - 32,  x, grid, out, sx, sy, simg, sacc);
    else if (r <  64) band<20, 4, 40>(b, r - 48,  x, grid, out, sx, sy, simg, sacc);
    else if (r <  80) band<24, 3, 40>(b, r - 64,  x, grid, out, sx, sy, simg, sacc);
    else if (r <  96) band<27, 2, 40>(b, r - 80,  x, grid, out, sx, sy, simg, sacc);
    else if (r < 112) band<29, 1, 40>(b, r - 96,  x, grid, out, sx, sy, simg, sacc);
    else              band<30, 2, 20>(b, r - 112, x, grid, out, sx, sy, simg, sacc);
}

extern "C" void kernel_launch(void* const* d_in, const int* in_sizes, int n_in,
                              void* d_out, int out_size, void* d_ws, size_t ws_size,
                              hipStream_t stream)
{
    const float* x    = (const float*)d_in[0];
    const float* lt   = (const float*)d_in[1];
    const float* grid = (const float*)d_in[2];
    float* out        = (float*)d_out;

    retina_polar_staged<<<dim3(B_ * 144), dim3(256), 0, stream>>>(x, lt, grid, out);
}

// Round 13
// 52.392 us; speedup vs baseline: 2.6572x; 1.3042x over previous
//
#include <hip/hip_runtime.h>
#include <hip/hip_fp16.h>

// retina_polar2: log-polar glimpse sampling + 10x10 avg-pool
// x: [64,3,512,512] f32 | l_t_prev: [64,2] f32 | grid_2d: [320,640,2] f32
// out: [64,3,32,64] f32
//
// Round-13 = r12 + two latency-chain cuts:
//  - staging: fixed 4-way row unroll, all 12 float4 loads issued upfront
//    (rows clamped to H-1; duplicate same-value writes benign) -> one
//    HBM latency round instead of four.
//  - gather: ZERO VMEM. grid_2d is separable (r[hu] * sincos[wu], same
//    f32 product rounding as the reference's outer product); per-block
//    LDS tables rtab[G*10]=256*exp(...), sctab[T]={sin,cos} replace the
//    10 global float2 reads per item with broadcast LDS reads + fmaf.
// Everything else as r12: 144 balanced blocks/image, f16 interleaved
// {c0,c1,c2,pad} tile + one ds_read_b64 per tap, analytic bbox, interior
// fast path, bijective ds_write_b128 accumulation (no atomics).

#define HI_ 512
#define WI_ 512
#define B_  64
#define PLANE_ (HI_ * WI_)
#define PITCH 68
#define TILEPIX (64 * PITCH)   // 4352 pixels * 8 B = 34816 B

__device__ __forceinline__ void dec3(const __half* __restrict__ s, int pix,
                                     float2& f01, float& c) {
    const uint2 q = *reinterpret_cast<const uint2*>(s + 4 * pix);
    f01 = __half22float2(*reinterpret_cast<const __half2*>(&q.x));
    const unsigned short hu = (unsigned short)(q.y & 0xffffu);
    c = __half2float(*reinterpret_cast<const __half*>(&hu));
}

template<int W0, int G, int T, bool INT>
__device__ __forceinline__ void gatherLoop(
    const int tid,
    const __half* __restrict__ simg,
    float* __restrict__ sacc,
    const float* __restrict__ rtab,
    const float2* __restrict__ sctab,
    const float sx, const float sy,
    const int xs4, const int y_lo, const int wmax, const int hmax)
{
    constexpr int ITEMS = T * G;
    for (int it = tid; it < ITEMS; it += 256) {
        const int tl    = it % T;
        const int win   = it / T;
        const float2 sc = sctab[tl];
        const int rbase = win * 10;

        int   pp [10];
        float wxv[10], wyv[10];
        #pragma unroll
        for (int j = 0; j < 10; ++j) {
            const float r2 = rtab[rbase + j];      // broadcast b32
            float ix = fmaf(r2, sc.x, sx);
            float iy = fmaf(r2, sc.y, sy);
            if (!INT) {
                ix = fminf(fmaxf(ix, 0.0f), 511.0f);
                iy = fminf(fmaxf(iy, 0.0f), 511.0f);
            }
            const float x0f = floorf(ix);
            const float y0f = floorf(iy);
            int col = (int)x0f - xs4;
            int row = (int)y0f - y_lo;
            if (!INT) {
                col = min(max(col, 0), wmax);
                row = min(max(row, 0), hmax);
            }
            pp [j] = row * PITCH + col;
            wxv[j] = ix - x0f;
            wyv[j] = iy - y0f;
        }

        float2 s01 = make_float2(0.0f, 0.0f);
        float  s2  = 0.0f;
        #pragma unroll
        for (int hh = 0; hh < 2; ++hh) {
            float2 f00[5], f01v[5], f10[5], f11[5];
            float  c00[5], c01[5], c10[5], c11[5];
            #pragma unroll
            for (int j = 0; j < 5; ++j) {
                const int p = pp[hh * 5 + j];
                dec3(simg, p,             f00[j],  c00[j]);
                dec3(simg, p + 1,         f01v[j], c01[j]);
                dec3(simg, p + PITCH,     f10[j],  c10[j]);
                dec3(simg, p + PITCH + 1, f11[j],  c11[j]);
            }
            #pragma unroll
            for (int j = 0; j < 5; ++j) {
                const int rr = hh * 5 + j;
                const float w11 = wxv[rr] * wyv[rr];
                const float w10 = wyv[rr] - w11;
                const float w01 = wxv[rr] - w11;
                const float w00 = 1.0f - wxv[rr] - wyv[rr] + w11;
                s01.x += f00[j].x*w00 + f01v[j].x*w01 + f10[j].x*w10 + f11[j].x*w11;
                s01.y += f00[j].y*w00 + f01v[j].y*w01 + f10[j].y*w10 + f11[j].y*w11;
                s2    += c00[j]  *w00 + c01[j]  *w01 + c10[j]  *w10 + c11[j]  *w11;
            }
        }

        // bijective slot (win,tc,ph) <-> it : one b128 store, no atomic
        *reinterpret_cast<float4*>(&sacc[it * 4]) =
            make_float4(s01.x, s01.y, s2, 0.0f);
    }
}

template<int W0, int G, int T>
__device__ __forceinline__ void band(
    const int b, const int slot,
    const float* __restrict__ x,
    float* __restrict__ out,
    const float sx, const float sy,
    __half*  __restrict__ simg,
    float*   __restrict__ sacc,
    float*   __restrict__ rtab,
    float2*  __restrict__ sctab)
{
    constexpr int TC   = T / 10;
    constexpr int ACCN = 3 * G * TC;
    const int tid = threadIdx.x;
    const int th0 = slot * T;

    const float CT  = 6.283185307179586f / 640.0f;
    const float LN001 = -4.605170185988091f;          // ln 0.01
    const float LSTEP = 4.0943445622221004f / 319.0f; // ln 60 / 319

    // ---- separable polar tables (once per block, ~120 transcendentals) ----
    if (tid < G * 10)
        rtab[tid] = 256.0f * expf(fmaf((float)(W0 * 10 + tid), LSTEP, LN001));
    const int t2 = tid - 128;
    if (t2 >= 0 && t2 < T) {
        const float th = (float)(th0 + t2) * CT;
        sctab[t2] = make_float2(sinf(th), cosf(th));
    }

    // ---- analytic bbox (exact range of 256*r*sin/cos over the band) ----
    const float tha = th0 * CT, thb = (th0 + T - 1) * CT;
    const float r_lo  = expf(fmaf((float)(10 * W0),           LSTEP, LN001));
    const float r_hi  = expf(fmaf((float)(10 * (W0 + G) - 1), LSTEP, LN001));
    const float plo = 256.0f * r_lo, phi = 256.0f * r_hi;

    const float sa = sinf(tha), sb = sinf(thb);
    const float ca = cosf(tha), cb = cosf(thb);
    const float smax = (tha < 1.5707965f && thb > 1.5707962f) ?  1.0f : fmaxf(sa, sb);
    const float smin = (tha < 4.7123892f && thb > 4.7123888f) ? -1.0f : fminf(sa, sb);
    const float cmax = fmaxf(ca, cb);
    const float cmin = (tha < 3.1415928f && thb > 3.1415925f) ? -1.0f : fminf(ca, cb);

    const float ixmin = fminf(fminf(plo*smin, phi*smin), fminf(plo*smax, phi*smax)) + sx;
    const float ixmax = fmaxf(fmaxf(plo*smin, phi*smin), fmaxf(plo*smax, phi*smax)) + sx;
    const float iymin = fminf(fminf(plo*cmin, phi*cmin), fminf(plo*cmax, phi*cmax)) + sy;
    const float iymax = fmaxf(fmaxf(plo*cmin, phi*cmin), fmaxf(plo*cmax, phi*cmax)) + sy;

    const int x_lo = max(0, (int)floorf(ixmin - 0.5f));
    const int x_hi = min(511, (int)ceilf(ixmax + 0.5f));
    const int y_lo = max(0, (int)floorf(iymin - 0.5f));
    const int y_hi = min(511, (int)ceilf(iymax + 0.5f));

    const int xs4 = x_lo & ~3;
    const int W4  = min(PITCH / 4, ((x_hi + 1 - xs4) >> 2) + 1);
    const int H   = min(64, y_hi - y_lo + 2);
    const int wmax = (W4 << 2) - 2;
    const int hmax = H - 2;

    const bool interior = (ixmin > 1.0f) && (ixmax < 510.0f) &&
                          (iymin > 1.0f) && (iymax < 510.0f);

    const float* __restrict__ xb = x + (size_t)b * 3 * PLANE_;

    // ---- stage: 4-way unrolled, 12 float4 loads issued upfront ----
    const int lane16 = tid & 15;
    const int rowB   = tid >> 4;
    {
        const int xb0 = xs4 + (lane16 << 2);
        if (lane16 < W4) {
            if (xb0 <= 508) {
                float4 v0[4], v1[4], v2[4];
                int rw[4];
                #pragma unroll
                for (int k = 0; k < 4; ++k) {
                    rw[k] = min(rowB + 16 * k, H - 1);
                    const int ys = min(y_lo + rw[k], 511);
                    const float* __restrict__ r0 = xb + ys * 512 + xb0;
                    v0[k] = *reinterpret_cast<const float4*>(r0);
                    v1[k] = *reinterpret_cast<const float4*>(r0 + PLANE_);
                    v2[k] = *reinterpret_cast<const float4*>(r0 + 2 * PLANE_);
                }
                #pragma unroll
                for (int k = 0; k < 4; ++k) {
                    const int pix0 = rw[k] * PITCH + (lane16 << 2);
                    const float* a0 = reinterpret_cast<const float*>(&v0[k]);
                    const float* a1 = reinterpret_cast<const float*>(&v1[k]);
                    const float* a2 = reinterpret_cast<const float*>(&v2[k]);
                    #pragma unroll
                    for (int p = 0; p < 4; ++p) {
                        __half* d = simg + 4 * (pix0 + p);
                        *reinterpret_cast<__half2*>(d) = __floats2half2_rn(a0[p], a1[p]);
                        d[2] = __float2half_rn(a2[p]);
                    }
                }
            } else {
                // rare right-edge case: scalar clamped loads
                #pragma unroll
                for (int k = 0; k < 4; ++k) {
                    const int rw = min(rowB + 16 * k, H - 1);
                    const int ys = min(y_lo + rw, 511);
                    const float* __restrict__ r0 = xb + ys * 512;
                    const int pix0 = rw * PITCH + (lane16 << 2);
                    #pragma unroll
                    for (int p = 0; p < 4; ++p) {
                        const int xs = min(xb0 + p, 511);
                        __half* d = simg + 4 * (pix0 + p);
                        *reinterpret_cast<__half2*>(d) =
                            __floats2half2_rn(r0[xs], r0[PLANE_ + xs]);
                        d[2] = __float2half_rn(r0[2 * PLANE_ + xs]);
                    }
                }
            }
        }
        // extra 17th float4 column (only when W4 == 17)
        for (int c4 = lane16 + 16; c4 < W4; c4 += 16) {
            const int xe = xs4 + (c4 << 2);
            #pragma unroll
            for (int k = 0; k < 4; ++k) {
                const int rw = min(rowB + 16 * k, H - 1);
                const int ys = min(y_lo + rw, 511);
                const float* __restrict__ r0 = xb + ys * 512;
                const int pix0 = rw * PITCH + (c4 << 2);
                #pragma unroll
                for (int p = 0; p < 4; ++p) {
                    const int xs = min(xe + p, 511);
                    __half* d = simg + 4 * (pix0 + p);
                    *reinterpret_cast<__half2*>(d) =
                        __floats2half2_rn(r0[xs], r0[PLANE_ + xs]);
                    d[2] = __float2half_rn(r0[2 * PLANE_ + xs]);
                }
            }
        }
    }
    __syncthreads();

    if (interior)
        gatherLoop<W0, G, T, true >(tid, simg, sacc, rtab, sctab, sx, sy, xs4, y_lo, wmax, hmax);
    else
        gatherLoop<W0, G, T, false>(tid, simg, sacc, rtab, sctab, sx, sy, xs4, y_lo, wmax, hmax);
    __syncthreads();

    // ---- output: sum the 10 radial-phase partials per (c,win,tc) ----
    if (tid < ACCN) {
        const int c   = tid / (G * TC);
        const int rem = tid - c * (G * TC);
        const int win = rem / TC;
        const int tc  = rem - win * TC;
        const int base = (win * T + tc * 10) * 4 + c;
        float s = 0.0f;
        #pragma unroll
        for (int ph = 0; ph < 10; ++ph)
            s += sacc[base + ph * 4];
        out[(((size_t)b * 3 + c) * 32 + W0 + win) * 64 + (th0 / 10) + tc] =
            s * 0.01f;
    }
}

__global__ __launch_bounds__(256, 4) void retina_polar_staged(
    const float* __restrict__ x,
    const float* __restrict__ lt,
    const float* __restrict__ grid,   // unused: grid is separable, rebuilt in LDS
    float* __restrict__ out)
{
    __shared__ __half  simg[TILEPIX * 4];   // 34816 B
    __shared__ float   sacc[1280];          // 5120 B
    __shared__ float   rtab[80];            // 320 B
    __shared__ float2  sctab[40];           // 320 B

    const int bid = blockIdx.x;
    const int b   = bid / 144;
    const int r   = bid - b * 144;
    const float sx = fmaf(lt[b * 2 + 0], 256.0f, 255.5f);
    const float sy = fmaf(lt[b * 2 + 1], 256.0f, 255.5f);

    if      (r <  16) band< 0, 8, 40>(b, r,       x, out, sx, sy, simg, sacc, rtab, sctab);
    else if (r <  32) band< 8, 7, 40>(b, r - 16,  x, out, sx, sy, simg, sacc, rtab, sctab);
    else if (r <  48) band<15, 5, 40>(b, r - 32,  x, out, sx, sy, simg, sacc, rtab, sctab);
    else if (r <  64) band<20, 4, 40>(b, r - 48,  x, out, sx, sy, simg, sacc, rtab, sctab);
    else if (r <  80) band<24, 3, 40>(b, r - 64,  x, out, sx, sy, simg, sacc, rtab, sctab);
    else if (r <  96) band<27, 2, 40>(b, r - 80,  x, out, sx, sy, simg, sacc, rtab, sctab);
    else if (r < 112) band<29, 1, 40>(b, r - 96,  x, out, sx, sy, simg, sacc, rtab, sctab);
    else              band<30, 2, 20>(b, r - 112, x, out, sx, sy, simg, sacc, rtab, sctab);
}

extern "C" void kernel_launch(void* const* d_in, const int* in_sizes, int n_in,
                              void* d_out, int out_size, void* d_ws, size_t ws_size,
                              hipStream_t stream)
{
    const float* x    = (const float*)d_in[0];
    const float* lt   = (const float*)d_in[1];
    const float* grid = (const float*)d_in[2];
    float* out        = (float*)d_out;

    retina_polar_staged<<<dim3(B_ * 144), dim3(256), 0, stream>>>(x, lt, grid, out);
}